// Round 2
// baseline (243.118 us; speedup 1.0000x reference)
//
#include <hip/hip_runtime.h>
#include <math.h>

#define HAND_PARAM_DIM 32
#define INF_DIST 1000000.0f
#define EPS 1e-8f
#define NROW 64        // B*S
#define HW_N 65536
#define NV 778
#define NMESH (2*NV)   // 1556
#define K_SEL 1024u
#define CAND_CAP 2048
#define HALF_BITS 0x3F000000u   // bits of 0.5f

// ---- workspace layout (bytes) ----
// region0 (1 MB) is time-shared: ghist (64*4096 u32) during hist/select,
// then cand (64*2048 u64) during collect/finalize (no temporal overlap).
#define OFF_REGION0   0u
#define OFF_CCOUNT    1048576u
#define OFF_PARAMS    1048832u      // 64 * {b1, r1, T, cut} u32
#define OFF_MESH      1049856u      // 64*1556 float4 (16B aligned)
#define OFF_PARTIAL   2643200u      // 1024 f32
#define OFF_PCOUNT    2647296u      // 1024 i32
#define ZERO_WORDS    262208        // ghist + ccount

// ---------------------------------------------------------------------------
__global__ void __launch_bounds__(256) zero_kernel(unsigned* __restrict__ p, int n) {
    int i = blockIdx.x * 256 + threadIdx.x;
    if (i < n) p[i] = 0u;
}

// ---------------------------------------------------------------------------
// Mesh points: one block per (row, hand).
// ---------------------------------------------------------------------------
__global__ void __launch_bounds__(256) mesh_kernel(
    const float* __restrict__ hp, const int* __restrict__ hv,
    const float* __restrict__ vtl, const float* __restrict__ vtr,
    const float* __restrict__ sdl, const float* __restrict__ sdr,
    const float* __restrict__ pdl, const float* __restrict__ pdr,
    float4* __restrict__ meshQ)
{
    int blk  = blockIdx.x;
    int row  = blk >> 1;
    int hand = blk & 1;
    const float* p = hp + row * (2 * HAND_PARAM_DIM) + hand * HAND_PARAM_DIM;
    int valid = hv[row * 2 + hand];

    const float* vt = hand ? vtr : vtl;
    const float* sd = hand ? sdr : sdl;
    const float* pd = hand ? pdr : pdl;

    float tx = p[0], ty = p[1], tz = p[2];
    float q0 = p[3], q1 = p[4], q2 = p[5], q3 = p[6];
    float qn = sqrtf(q0*q0 + q1*q1 + q2*q2 + q3*q3 + EPS);
    float inv = 1.0f / fmaxf(qn, EPS);
    q0 *= inv; q1 *= inv; q2 *= inv; q3 *= inv;
    float sgn = (q0 < 0.0f) ? -1.0f : 1.0f;
    q0 *= sgn; q1 *= sgn; q2 *= sgn; q3 *= sgn;
    float sin_half = sqrtf(q1*q1 + q2*q2 + q3*q3 + EPS);
    float w_safe = fminf(fmaxf(q0, -1.0f + EPS), 1.0f - EPS);
    float ang2 = 2.0f * atan2f(sin_half, w_safe);
    float factor = (sin_half < 1e-6f) ? 2.0f : ang2 / fmaxf(sin_half, EPS);
    float rx = q1 * factor, ry = q2 * factor, rz = q3 * factor;
    float ang = sqrtf(rx*rx + ry*ry + rz*rz + EPS);
    float iang = 1.0f / ang;
    float ax = rx * iang, ay = ry * iang, az = rz * iang;
    float c = cosf(ang), s = sinf(ang), omc = 1.0f - c;

    float pose[15], betas[10];
#pragma unroll
    for (int k = 0; k < 15; k++) pose[k] = p[7 + k];
#pragma unroll
    for (int k = 0; k < 10; k++) betas[k] = p[22 + k];

    for (int v = threadIdx.x; v < NV; v += blockDim.x) {
        float px = vt[v*3+0], py = vt[v*3+1], pz = vt[v*3+2];
        const float* sdv = sd + v * 30;
#pragma unroll
        for (int k = 0; k < 10; k++) {
            px = fmaf(sdv[k],      betas[k], px);
            py = fmaf(sdv[10 + k], betas[k], py);
            pz = fmaf(sdv[20 + k], betas[k], pz);
        }
        const float* pdv = pd + v * 45;
#pragma unroll
        for (int k = 0; k < 15; k++) {
            px = fmaf(pdv[k],      pose[k], px);
            py = fmaf(pdv[15 + k], pose[k], py);
            pz = fmaf(pdv[30 + k], pose[k], pz);
        }
        float cx = ay * pz - az * py;
        float cy = az * px - ax * pz;
        float cz = ax * py - ay * px;
        float kdv = ax * px + ay * py + az * pz;
        float ox = px * c + cx * s + ax * kdv * omc + tx;
        float oy = py * c + cy * s + ay * kdv * omc + ty;
        float oz = pz * c + cz * s + az * kdv * omc + tz;
        if (!valid) { ox = INF_DIST; oy = INF_DIST; oz = INF_DIST; }
        meshQ[row * NMESH + hand * NV + v] = make_float4(ox, oy, oz, 0.0f);
    }
}

// ---------------------------------------------------------------------------
// B1: per-row 4096-bin histogram on float bits >> 18. 1024 blocks.
// ---------------------------------------------------------------------------
__global__ void __launch_bounds__(256) hist_kernel(
    const float* __restrict__ mask, const int* __restrict__ hv,
    unsigned* __restrict__ ghist)
{
    int row = blockIdx.x >> 4, chunk = blockIdx.x & 15;
    if (!(hv[row*2] | hv[row*2+1])) return;
    int t = threadIdx.x;
    __shared__ unsigned lh[4096];
    for (int i = t; i < 4096; i += 256) lh[i] = 0u;
    __syncthreads();
    const float* m = mask + (size_t)row * HW_N + chunk * 4096;
#pragma unroll
    for (int j = 0; j < 16; j++) {
        unsigned u = __float_as_uint(m[j*256 + t]);
        unsigned b = u >> 18; if (b > 4095u) b = 4095u;
        atomicAdd(&lh[b], 1u);
    }
    __syncthreads();
    for (int i = t; i < 4096; i += 256) {
        unsigned v = lh[i];
        if (v) atomicAdd(&ghist[row*4096 + i], v);
    }
}

// ---------------------------------------------------------------------------
// B2: per-row scan of 4096-bin hist -> (b1, r1). 64 blocks.
// ---------------------------------------------------------------------------
__global__ void __launch_bounds__(256) select_bin_kernel(
    const unsigned* __restrict__ ghist, const int* __restrict__ hv,
    unsigned* __restrict__ params)
{
    __shared__ unsigned bins[4096];
    __shared__ unsigned seg[256];
    __shared__ unsigned sb1, sr1;
    int row = blockIdx.x;
    int t = threadIdx.x;
    if (!(hv[row*2] | hv[row*2+1])) {
        if (t == 0) { params[row*4+0] = 0xFFFFFFFFu; params[row*4+1] = 0u; }
        return;
    }
    for (int i = t; i < 4096; i += 256) bins[i] = ghist[row*4096 + i];
    __syncthreads();
    unsigned s = 0;
#pragma unroll
    for (int k = 0; k < 16; k++) s += bins[t*16 + k];
    seg[t] = s;
    __syncthreads();
    for (int off = 1; off < 256; off <<= 1) {        // inclusive suffix scan
        unsigned v = (t + off < 256) ? seg[t+off] : 0u;
        __syncthreads();
        seg[t] += v;
        __syncthreads();
    }
    unsigned running = (t < 255) ? seg[t+1] : 0u;    // suffix strictly after segment
    for (int k = 15; k >= 0; k--) {
        unsigned nb = running + bins[t*16 + k];
        if (nb >= K_SEL && running < K_SEL) { sb1 = (unsigned)(t*16 + k); sr1 = K_SEL - running; }
        running = nb;
    }
    __syncthreads();
    if (t == 0) { params[row*4+0] = sb1; params[row*4+1] = sr1; }
}

// ---------------------------------------------------------------------------
// B3: collect (value,index) of all elements in threshold bin. 1024 blocks.
// Order in cand buffer is nondeterministic but B4's result is order-invariant.
// ---------------------------------------------------------------------------
__global__ void __launch_bounds__(256) collect_kernel(
    const float* __restrict__ mask, const unsigned* __restrict__ params,
    unsigned long long* __restrict__ cand, unsigned* __restrict__ ccount)
{
    int row = blockIdx.x >> 4, chunk = blockIdx.x & 15;
    unsigned b1 = params[row*4+0];
    if (b1 > 4095u) return;
    int t = threadIdx.x;
    const float* m = mask + (size_t)row * HW_N;
    int base = chunk * 4096;
#pragma unroll
    for (int j = 0; j < 16; j++) {
        int eidx = base + j*256 + t;
        unsigned u = __float_as_uint(m[eidx]);
        if ((u >> 18) == b1) {
            unsigned p = atomicAdd(&ccount[row], 1u);
            if (p < CAND_CAP)
                cand[(size_t)row * CAND_CAP + p] = ((unsigned long long)u << 32) | (unsigned)eidx;
        }
    }
}

// ---------------------------------------------------------------------------
// B4: exact threshold T and tie index cutoff among candidates. 64 blocks.
// ---------------------------------------------------------------------------
__global__ void __launch_bounds__(256) finalize_kernel(
    const unsigned long long* __restrict__ cand, const unsigned* __restrict__ ccount,
    unsigned* __restrict__ params)
{
    __shared__ unsigned cval[CAND_CAP], cidx[CAND_CAP];
    __shared__ unsigned h[512];
    __shared__ unsigned seg[256];
    __shared__ unsigned ss1, sR2, slo1, sR3;
    __shared__ unsigned tlist[256];
    __shared__ unsigned tn;
    int row = blockIdx.x, t = threadIdx.x;
    unsigned b1 = params[row*4+0];
    if (b1 > 4095u) {
        if (t == 0) { params[row*4+2] = 0xFFFFFFFFu; params[row*4+3] = 0u; }
        return;
    }
    unsigned cnt = ccount[row]; if (cnt > CAND_CAP) cnt = CAND_CAP;
    if (cnt == 0) {
        if (t == 0) { params[row*4+2] = 0xFFFFFFFFu; params[row*4+3] = 0u; }
        return;
    }
    unsigned R = params[row*4+1];
    if (R > cnt) R = cnt;
    if (R < 1) R = 1;
    for (unsigned i = t; i < cnt; i += 256) {
        unsigned long long c = cand[(size_t)row * CAND_CAP + i];
        cval[i] = (unsigned)(c >> 32); cidx[i] = (unsigned)c;
    }
    h[t] = 0u; h[t+256] = 0u;
    if (t == 0) tn = 0u;
    __syncthreads();
    // phase A: 512 bins on bits[17:9]
    for (unsigned i = t; i < cnt; i += 256) atomicAdd(&h[(cval[i] >> 9) & 0x1FFu], 1u);
    __syncthreads();
    seg[t] = h[2*t] + h[2*t+1];
    __syncthreads();
    for (int off = 1; off < 256; off <<= 1) {
        unsigned v = (t + off < 256) ? seg[t+off] : 0u;
        __syncthreads(); seg[t] += v; __syncthreads();
    }
    {
        unsigned running = (t < 255) ? seg[t+1] : 0u;
        for (int k = 1; k >= 0; k--) {
            unsigned nb = running + h[2*t + k];
            if (nb >= R && running < R) { ss1 = (unsigned)(2*t + k); sR2 = R - running; }
            running = nb;
        }
    }
    __syncthreads();
    unsigned s1 = ss1, R2 = sR2;
    h[t] = 0u; h[t+256] = 0u;
    __syncthreads();
    // phase B: 512 bins on bits[8:0] among prefix matches
    for (unsigned i = t; i < cnt; i += 256)
        if (((cval[i] >> 9) & 0x1FFu) == s1) atomicAdd(&h[cval[i] & 0x1FFu], 1u);
    __syncthreads();
    seg[t] = h[2*t] + h[2*t+1];
    __syncthreads();
    for (int off = 1; off < 256; off <<= 1) {
        unsigned v = (t + off < 256) ? seg[t+off] : 0u;
        __syncthreads(); seg[t] += v; __syncthreads();
    }
    {
        unsigned running = (t < 255) ? seg[t+1] : 0u;
        for (int k = 1; k >= 0; k--) {
            unsigned nb = running + h[2*t + k];
            if (nb >= R2 && running < R2) { slo1 = (unsigned)(2*t + k); sR3 = R2 - running; }
            running = nb;
        }
    }
    __syncthreads();
    unsigned T = (b1 << 18) | (s1 << 9) | slo1;
    // phase C: ties at exact value T -> pick R3-th smallest index
    for (unsigned i = t; i < cnt; i += 256) {
        if (cval[i] == T) {
            unsigned p = atomicAdd(&tn, 1u);
            if (p < 256u) tlist[p] = cidx[i];
        }
    }
    __syncthreads();
    if (t == 0) {
        unsigned nt2 = (tn < 256u) ? tn : 256u;
        for (unsigned a = 1; a < nt2; a++) {
            unsigned key = tlist[a]; int b = (int)a - 1;
            while (b >= 0 && tlist[b] > key) { tlist[b+1] = tlist[b]; b--; }
            tlist[b+1] = key;
        }
        unsigned r = sR3;
        if (r > nt2) r = nt2;
        if (r < 1) r = 1;
        params[row*4+2] = T;
        params[row*4+3] = (nt2 > 0) ? tlist[r-1] : 0u;
    }
}

// ---------------------------------------------------------------------------
// C: fused select + NN distance + block partial sum. 1024 blocks (16/row).
// ---------------------------------------------------------------------------
__global__ void __launch_bounds__(256) dist_kernel(
    const float4* __restrict__ meshQ, const float* __restrict__ mask,
    const float* __restrict__ means, const int* __restrict__ hv,
    const unsigned* __restrict__ params,
    float* __restrict__ partial, int* __restrict__ pcount)
{
    __shared__ float4 mq[NMESH];
    __shared__ unsigned scn[256];
    __shared__ unsigned slist[1024];
    __shared__ float red[256];
    int blk = blockIdx.x;
    int row = blk >> 4, chunk = blk & 15;
    int t = threadIdx.x;
    if (!(hv[row*2] | hv[row*2+1])) {
        if (t == 0) { partial[blk] = 0.0f; pcount[blk] = 0; }
        return;
    }
    for (int i = t; i < NMESH; i += 256) mq[i] = meshQ[row * NMESH + i];
    unsigned T = params[row*4+2], cut = params[row*4+3];
    const float* m = mask + (size_t)row * HW_N;
    int base = chunk * 4096;
    int c = 0;
#pragma unroll
    for (int j = 0; j < 16; j++) {
        int eidx = base + j*256 + t;
        unsigned u = __float_as_uint(m[eidx]);
        if ((u > T || (u == T && (unsigned)eidx <= cut)) && u > HALF_BITS) c++;
    }
    scn[t] = (unsigned)c;
    __syncthreads();
    for (int off = 1; off < 256; off <<= 1) {        // inclusive prefix scan
        unsigned v = (t >= off) ? scn[t-off] : 0u;
        __syncthreads(); scn[t] += v; __syncthreads();
    }
    unsigned pos = scn[t] - (unsigned)c;
#pragma unroll
    for (int j = 0; j < 16; j++) {
        int eidx = base + j*256 + t;
        unsigned u = __float_as_uint(m[eidx]);
        if ((u > T || (u == T && (unsigned)eidx <= cut)) && u > HALF_BITS)
            slist[pos++] = (unsigned)eidx;
    }
    __syncthreads();
    int nsel = (int)scn[255];
    float acc = 0.0f;
    for (int sidx = t; sidx < nsel; sidx += 256) {
        unsigned eidx = slist[sidx];
        const float* g = means + ((size_t)row * HW_N + eidx) * 3;
        float sx = g[0], sy = g[1], sz = g[2];
        float m0 = 3.4e38f, m1 = m0, m2 = m0, m3 = m0;
        for (int p = 0; p < NMESH; p += 4) {
            float4 a0 = mq[p], a1 = mq[p+1], a2 = mq[p+2], a3 = mq[p+3];
            float dx0 = sx - a0.x, dy0 = sy - a0.y, dz0 = sz - a0.z;
            m0 = fminf(m0, fmaf(dx0, dx0, fmaf(dy0, dy0, dz0 * dz0)));
            float dx1 = sx - a1.x, dy1 = sy - a1.y, dz1 = sz - a1.z;
            m1 = fminf(m1, fmaf(dx1, dx1, fmaf(dy1, dy1, dz1 * dz1)));
            float dx2 = sx - a2.x, dy2 = sy - a2.y, dz2 = sz - a2.z;
            m2 = fminf(m2, fmaf(dx2, dx2, fmaf(dy2, dy2, dz2 * dz2)));
            float dx3 = sx - a3.x, dy3 = sy - a3.y, dz3 = sz - a3.z;
            m3 = fminf(m3, fmaf(dx3, dx3, fmaf(dy3, dy3, dz3 * dz3)));
        }
        acc += fminf(fminf(m0, m1), fminf(m2, m3));
    }
    red[t] = acc;
    __syncthreads();
    for (int off = 128; off > 0; off >>= 1) {
        if (t < off) red[t] += red[t+off];
        __syncthreads();
    }
    if (t == 0) { partial[blk] = red[0]; pcount[blk] = nsel; }
}

// ---------------------------------------------------------------------------
// D: final reduce over 1024 block partials.
// ---------------------------------------------------------------------------
__global__ void __launch_bounds__(256) finish_kernel(
    const float* __restrict__ partial, const int* __restrict__ pcount,
    float* __restrict__ out)
{
    __shared__ double rs[256];
    __shared__ int rc[256];
    int t = threadIdx.x;
    double s = 0.0; int c = 0;
#pragma unroll
    for (int k = 0; k < 4; k++) { s += (double)partial[t + k*256]; c += pcount[t + k*256]; }
    rs[t] = s; rc[t] = c;
    __syncthreads();
    for (int off = 128; off > 0; off >>= 1) {
        if (t < off) { rs[t] += rs[t+off]; rc[t] += rc[t+off]; }
        __syncthreads();
    }
    if (t == 0) {
        int n = rc[0] > 1 ? rc[0] : 1;
        out[0] = (float)(rs[0] / (double)n);
    }
}

extern "C" void kernel_launch(void* const* d_in, const int* in_sizes, int n_in,
                              void* d_out, int out_size, void* d_ws, size_t ws_size,
                              hipStream_t stream) {
    const float* hp    = (const float*)d_in[0];
    const float* means = (const float*)d_in[1];
    const float* mask  = (const float*)d_in[2];
    const int*   hv    = (const int*)  d_in[3];
    const float* vtl   = (const float*)d_in[4];
    const float* vtr   = (const float*)d_in[5];
    const float* sdl   = (const float*)d_in[6];
    const float* sdr   = (const float*)d_in[7];
    const float* pdl   = (const float*)d_in[8];
    const float* pdr   = (const float*)d_in[9];
    float* out = (float*)d_out;

    char* ws = (char*)d_ws;
    unsigned*           ghist   = (unsigned*)(ws + OFF_REGION0);
    unsigned long long* cand    = (unsigned long long*)(ws + OFF_REGION0);
    unsigned*           ccount  = (unsigned*)(ws + OFF_CCOUNT);
    unsigned*           params  = (unsigned*)(ws + OFF_PARAMS);
    float4*             meshQ   = (float4*)(ws + OFF_MESH);
    float*              partial = (float*)(ws + OFF_PARTIAL);
    int*                pcount  = (int*)(ws + OFF_PCOUNT);

    zero_kernel<<<(ZERO_WORDS + 255) / 256, 256, 0, stream>>>(ghist, ZERO_WORDS);
    mesh_kernel<<<NROW * 2, 256, 0, stream>>>(hp, hv, vtl, vtr, sdl, sdr, pdl, pdr, meshQ);
    hist_kernel<<<NROW * 16, 256, 0, stream>>>(mask, hv, ghist);
    select_bin_kernel<<<NROW, 256, 0, stream>>>(ghist, hv, params);
    collect_kernel<<<NROW * 16, 256, 0, stream>>>(mask, params, cand, ccount);
    finalize_kernel<<<NROW, 256, 0, stream>>>(cand, ccount, params);
    dist_kernel<<<NROW * 16, 256, 0, stream>>>(meshQ, mask, means, hv, params, partial, pcount);
    finish_kernel<<<1, 256, 0, stream>>>(partial, pcount, out);
}

// Round 3
// 64.085 us; speedup vs baseline: 3.7937x; 3.7937x over previous
//
#include <hip/hip_runtime.h>
#include <math.h>

#define HAND_PARAM_DIM 32
#define INF_DIST 1000000.0f
#define EPS 1e-8f
#define NROW 64        // B*S
#define HW_N 65536
#define NV 778
#define NMESH 1556
#define K_SEL 1024u
#define HALF_BITS 0x3F000000u   // bits of 0.5f
#define ROW_CAP 2048
#define CHUNK_CAP 320
#define FIX_SCALE 4294967296.0  // 2^32 fixed-point scale

// ---- workspace layout (bytes) ----
// ghist (1MB) is dead after select_bin; cand overlays it (written by collect).
#define OFF_GHIST  0u           // 64*4096*4 = 1048576
#define OFF_CAND   0u           // 64*2048*8 = 1048576 (overlay)
#define OFF_CCOUNT 1048576u     // 64 u32
#define OFF_DCOUNT 1048832u     // 64 u32
#define OFF_PARAMS 1049088u     // 64*2 u32 {b1, r1}
#define OFF_DLIST  1050112u     // 64*2048*8 = 1048576
#define OFF_MESH   2098688u     // 64*1556*16 = 1593344
#define OFF_PART   3692032u     // 1024 * 8 (i64)
#define OFF_PCNT   3700224u     // 1024 * 4
#define ZERO_U4    65568        // (ghist + ccount + dcount) bytes/16
#define ZB         80           // zero blocks appended to mesh grid

static __device__ __forceinline__ unsigned umin_(unsigned a, unsigned b){ return a < b ? a : b; }

// ---------------------------------------------------------------------------
// Kernel 1: MANO mesh points (blocks 0..127) + workspace zeroing (blocks 128+).
// mesh.w = |p|^2 so dist can use the sb - 2*dot form.
// ---------------------------------------------------------------------------
__global__ void __launch_bounds__(256) mesh_zero_kernel(
    const float* __restrict__ hp, const int* __restrict__ hv,
    const float* __restrict__ vtl, const float* __restrict__ vtr,
    const float* __restrict__ sdl, const float* __restrict__ sdr,
    const float* __restrict__ pdl, const float* __restrict__ pdr,
    float4* __restrict__ meshQ, uint4* __restrict__ zbase)
{
    int blk = blockIdx.x;
    if (blk >= 128) {
        int zi = (blk - 128) * 256 + threadIdx.x;
        for (int i = zi; i < ZERO_U4; i += ZB * 256)
            zbase[i] = make_uint4(0u, 0u, 0u, 0u);
        return;
    }
    int row  = blk >> 1;
    int hand = blk & 1;
    const float* p = hp + row * (2 * HAND_PARAM_DIM) + hand * HAND_PARAM_DIM;
    int valid = hv[row * 2 + hand];

    const float* vt = hand ? vtr : vtl;
    const float* sd = hand ? sdr : sdl;
    const float* pd = hand ? pdr : pdl;

    float tx = p[0], ty = p[1], tz = p[2];
    float q0 = p[3], q1 = p[4], q2 = p[5], q3 = p[6];
    float qn = sqrtf(q0*q0 + q1*q1 + q2*q2 + q3*q3 + EPS);
    float inv = 1.0f / fmaxf(qn, EPS);
    q0 *= inv; q1 *= inv; q2 *= inv; q3 *= inv;
    float sgn = (q0 < 0.0f) ? -1.0f : 1.0f;
    q0 *= sgn; q1 *= sgn; q2 *= sgn; q3 *= sgn;
    float sin_half = sqrtf(q1*q1 + q2*q2 + q3*q3 + EPS);
    float w_safe = fminf(fmaxf(q0, -1.0f + EPS), 1.0f - EPS);
    float ang2 = 2.0f * atan2f(sin_half, w_safe);
    float factor = (sin_half < 1e-6f) ? 2.0f : ang2 / fmaxf(sin_half, EPS);
    float rx = q1 * factor, ry = q2 * factor, rz = q3 * factor;
    float ang = sqrtf(rx*rx + ry*ry + rz*rz + EPS);
    float iang = 1.0f / ang;
    float ax = rx * iang, ay = ry * iang, az = rz * iang;
    float c = cosf(ang), s = sinf(ang), omc = 1.0f - c;

    float pose[15], betas[10];
#pragma unroll
    for (int k = 0; k < 15; k++) pose[k] = p[7 + k];
#pragma unroll
    for (int k = 0; k < 10; k++) betas[k] = p[22 + k];

    for (int v = threadIdx.x; v < NV; v += blockDim.x) {
        float px = vt[v*3+0], py = vt[v*3+1], pz = vt[v*3+2];
        const float* sdv = sd + v * 30;
#pragma unroll
        for (int k = 0; k < 10; k++) {
            px = fmaf(sdv[k],      betas[k], px);
            py = fmaf(sdv[10 + k], betas[k], py);
            pz = fmaf(sdv[20 + k], betas[k], pz);
        }
        const float* pdv = pd + v * 45;
#pragma unroll
        for (int k = 0; k < 15; k++) {
            px = fmaf(pdv[k],      pose[k], px);
            py = fmaf(pdv[15 + k], pose[k], py);
            pz = fmaf(pdv[30 + k], pose[k], pz);
        }
        float cx = ay * pz - az * py;
        float cy = az * px - ax * pz;
        float cz = ax * py - ay * px;
        float kdv = ax * px + ay * py + az * pz;
        float ox = px * c + cx * s + ax * kdv * omc + tx;
        float oy = py * c + cy * s + ay * kdv * omc + ty;
        float oz = pz * c + cz * s + az * kdv * omc + tz;
        if (!valid) { ox = INF_DIST; oy = INF_DIST; oz = INF_DIST; }
        float sb = fmaf(ox, ox, fmaf(oy, oy, oz * oz));
        meshQ[row * NMESH + hand * NV + v] = make_float4(ox, oy, oz, sb);
    }
}

// ---------------------------------------------------------------------------
// Kernel 2: per-row 4096-bin histogram on float bits >> 18. 1024 blocks.
// ---------------------------------------------------------------------------
__global__ void __launch_bounds__(256) hist_kernel(
    const float* __restrict__ mask, const int* __restrict__ hv,
    unsigned* __restrict__ ghist)
{
    int row = blockIdx.x >> 4, chunk = blockIdx.x & 15;
    if (!(hv[row*2] | hv[row*2+1])) return;
    int t = threadIdx.x;
    __shared__ unsigned lh[4096];
    for (int i = t; i < 4096; i += 256) lh[i] = 0u;
    __syncthreads();
    const float4* m4 = (const float4*)(mask + (size_t)row * HW_N + chunk * 4096);
#pragma unroll
    for (int k = 0; k < 4; k++) {
        float4 v = m4[k*256 + t];
        unsigned b0 = __float_as_uint(v.x) >> 18; if (b0 > 4095u) b0 = 4095u;
        unsigned b1 = __float_as_uint(v.y) >> 18; if (b1 > 4095u) b1 = 4095u;
        unsigned b2 = __float_as_uint(v.z) >> 18; if (b2 > 4095u) b2 = 4095u;
        unsigned b3 = __float_as_uint(v.w) >> 18; if (b3 > 4095u) b3 = 4095u;
        atomicAdd(&lh[b0], 1u); atomicAdd(&lh[b1], 1u);
        atomicAdd(&lh[b2], 1u); atomicAdd(&lh[b3], 1u);
    }
    __syncthreads();
    for (int i = t; i < 4096; i += 256) {
        unsigned v = lh[i];
        if (v) atomicAdd(&ghist[row*4096 + i], v);
    }
}

// ---------------------------------------------------------------------------
// Kernel 3: per-row scan of 4096-bin hist -> (b1, r1). 64 blocks.
// ---------------------------------------------------------------------------
__global__ void __launch_bounds__(256) select_bin_kernel(
    const unsigned* __restrict__ ghist, const int* __restrict__ hv,
    unsigned* __restrict__ params)
{
    __shared__ unsigned bins[4096];
    __shared__ unsigned seg[256];
    __shared__ unsigned sb1, sr1;
    int row = blockIdx.x;
    int t = threadIdx.x;
    if (!(hv[row*2] | hv[row*2+1])) {
        if (t == 0) { params[row*2+0] = 0xFFFFFFFFu; params[row*2+1] = 0u; }
        return;
    }
    for (int i = t; i < 4096; i += 256) bins[i] = ghist[row*4096 + i];
    __syncthreads();
    unsigned s = 0;
#pragma unroll
    for (int k = 0; k < 16; k++) s += bins[t*16 + k];
    seg[t] = s;
    __syncthreads();
    for (int off = 1; off < 256; off <<= 1) {        // inclusive suffix scan
        unsigned v = (t + off < 256) ? seg[t+off] : 0u;
        __syncthreads();
        seg[t] += v;
        __syncthreads();
    }
    unsigned running = (t < 255) ? seg[t+1] : 0u;
    for (int k = 15; k >= 0; k--) {
        unsigned nb = running + bins[t*16 + k];
        if (nb >= K_SEL && running < K_SEL) { sb1 = (unsigned)(t*16 + k); sr1 = K_SEL - running; }
        running = nb;
    }
    __syncthreads();
    if (t == 0) { params[row*2+0] = sb1; params[row*2+1] = sr1; }
}

// ---------------------------------------------------------------------------
// Kernel 4: compaction. Definites (bin > b1) -> dlist, bin==b1 -> cand.
// LDS staging; ONE global atomic per block per list (was ~1 per element).
// ---------------------------------------------------------------------------
__global__ void __launch_bounds__(256) collect_kernel(
    const float* __restrict__ mask, const unsigned* __restrict__ params,
    unsigned long long* __restrict__ cand, unsigned* __restrict__ ccount,
    unsigned long long* __restrict__ dlist, unsigned* __restrict__ dcount)
{
    int row = blockIdx.x >> 4, chunk = blockIdx.x & 15;
    unsigned b1 = params[row*2];
    if (b1 > 4095u) return;
    int t = threadIdx.x;
    __shared__ unsigned long long dloc[CHUNK_CAP], cloc[CHUNK_CAP];
    __shared__ unsigned nd, nc, bd, bc;
    if (t == 0) { nd = 0u; nc = 0u; }
    __syncthreads();
    const float4* m4 = (const float4*)(mask + (size_t)row * HW_N + chunk * 4096);
#pragma unroll
    for (int k = 0; k < 4; k++) {
        float4 v = m4[k*256 + t];
        unsigned e0 = (unsigned)(chunk*4096 + k*1024 + t*4);
        unsigned uu0 = __float_as_uint(v.x), uu1 = __float_as_uint(v.y);
        unsigned uu2 = __float_as_uint(v.z), uu3 = __float_as_uint(v.w);
        unsigned bb;
        bb = uu0 >> 18;
        if (bb > b1)       { unsigned p = atomicAdd(&nd,1u); if (p < CHUNK_CAP) dloc[p] = ((unsigned long long)uu0<<32)|(e0+0u); }
        else if (bb == b1) { unsigned p = atomicAdd(&nc,1u); if (p < CHUNK_CAP) cloc[p] = ((unsigned long long)uu0<<32)|(e0+0u); }
        bb = uu1 >> 18;
        if (bb > b1)       { unsigned p = atomicAdd(&nd,1u); if (p < CHUNK_CAP) dloc[p] = ((unsigned long long)uu1<<32)|(e0+1u); }
        else if (bb == b1) { unsigned p = atomicAdd(&nc,1u); if (p < CHUNK_CAP) cloc[p] = ((unsigned long long)uu1<<32)|(e0+1u); }
        bb = uu2 >> 18;
        if (bb > b1)       { unsigned p = atomicAdd(&nd,1u); if (p < CHUNK_CAP) dloc[p] = ((unsigned long long)uu2<<32)|(e0+2u); }
        else if (bb == b1) { unsigned p = atomicAdd(&nc,1u); if (p < CHUNK_CAP) cloc[p] = ((unsigned long long)uu2<<32)|(e0+2u); }
        bb = uu3 >> 18;
        if (bb > b1)       { unsigned p = atomicAdd(&nd,1u); if (p < CHUNK_CAP) dloc[p] = ((unsigned long long)uu3<<32)|(e0+3u); }
        else if (bb == b1) { unsigned p = atomicAdd(&nc,1u); if (p < CHUNK_CAP) cloc[p] = ((unsigned long long)uu3<<32)|(e0+3u); }
    }
    __syncthreads();
    if (t == 0) {
        bd = atomicAdd(&dcount[row], umin_(nd, CHUNK_CAP));
        bc = atomicAdd(&ccount[row], umin_(nc, CHUNK_CAP));
    }
    __syncthreads();
    unsigned d = umin_(nd, CHUNK_CAP), c = umin_(nc, CHUNK_CAP);
    for (unsigned i = t; i < d; i += 256) {
        unsigned p = bd + i;
        if (p < ROW_CAP) dlist[(size_t)row * ROW_CAP + p] = dloc[i];
    }
    for (unsigned i = t; i < c; i += 256) {
        unsigned p = bc + i;
        if (p < ROW_CAP) cand[(size_t)row * ROW_CAP + p] = cloc[i];
    }
}

// ---------------------------------------------------------------------------
// Kernel 5: exact in-bin selection; append the r1 selected entries to dlist.
// ---------------------------------------------------------------------------
__global__ void __launch_bounds__(256) finalize_kernel(
    const unsigned long long* __restrict__ cand, const unsigned* __restrict__ ccount,
    const unsigned* __restrict__ params,
    unsigned long long* __restrict__ dlist, unsigned* __restrict__ dcount)
{
    __shared__ unsigned cval[ROW_CAP], cidx[ROW_CAP];
    __shared__ unsigned h[512];
    __shared__ unsigned seg[256];
    __shared__ unsigned ss1, sR2, slo1, sR3, sbase, sns, scut;
    __shared__ unsigned tlist[256];
    __shared__ unsigned tn;
    int row = blockIdx.x, t = threadIdx.x;
    unsigned b1 = params[row*2];
    if (b1 > 4095u) return;
    unsigned cnt = ccount[row]; if (cnt > ROW_CAP) cnt = ROW_CAP;
    if (cnt == 0) return;
    unsigned R = params[row*2+1];
    if (R > cnt) R = cnt;
    if (R < 1) R = 1;
    for (unsigned i = t; i < cnt; i += 256) {
        unsigned long long cc = cand[(size_t)row * ROW_CAP + i];
        cval[i] = (unsigned)(cc >> 32); cidx[i] = (unsigned)cc;
    }
    h[t] = 0u; h[t+256] = 0u;
    if (t == 0) { tn = 0u; sns = 0u; }
    __syncthreads();
    // phase A: 512 bins on bits[17:9]
    for (unsigned i = t; i < cnt; i += 256) atomicAdd(&h[(cval[i] >> 9) & 0x1FFu], 1u);
    __syncthreads();
    seg[t] = h[2*t] + h[2*t+1];
    __syncthreads();
    for (int off = 1; off < 256; off <<= 1) {
        unsigned v = (t + off < 256) ? seg[t+off] : 0u;
        __syncthreads(); seg[t] += v; __syncthreads();
    }
    {
        unsigned running = (t < 255) ? seg[t+1] : 0u;
        for (int k = 1; k >= 0; k--) {
            unsigned nb = running + h[2*t + k];
            if (nb >= R && running < R) { ss1 = (unsigned)(2*t + k); sR2 = R - running; }
            running = nb;
        }
    }
    __syncthreads();
    unsigned s1 = ss1, R2 = sR2;
    h[t] = 0u; h[t+256] = 0u;
    __syncthreads();
    // phase B: 512 bins on bits[8:0] among prefix matches
    for (unsigned i = t; i < cnt; i += 256)
        if (((cval[i] >> 9) & 0x1FFu) == s1) atomicAdd(&h[cval[i] & 0x1FFu], 1u);
    __syncthreads();
    seg[t] = h[2*t] + h[2*t+1];
    __syncthreads();
    for (int off = 1; off < 256; off <<= 1) {
        unsigned v = (t + off < 256) ? seg[t+off] : 0u;
        __syncthreads(); seg[t] += v; __syncthreads();
    }
    {
        unsigned running = (t < 255) ? seg[t+1] : 0u;
        for (int k = 1; k >= 0; k--) {
            unsigned nb = running + h[2*t + k];
            if (nb >= R2 && running < R2) { slo1 = (unsigned)(2*t + k); sR3 = R2 - running; }
            running = nb;
        }
    }
    __syncthreads();
    unsigned T = (b1 << 18) | (s1 << 9) | slo1;
    // ties at exact value T -> R3-th smallest index is the cut
    for (unsigned i = t; i < cnt; i += 256) {
        if (cval[i] == T) {
            unsigned p = atomicAdd(&tn, 1u);
            if (p < 256u) tlist[p] = cidx[i];
        }
    }
    __syncthreads();
    if (t == 0) {
        unsigned n2 = (tn < 256u) ? tn : 256u;
        for (unsigned a = 1; a < n2; a++) {
            unsigned key = tlist[a]; int b = (int)a - 1;
            while (b >= 0 && tlist[b] > key) { tlist[b+1] = tlist[b]; b--; }
            tlist[b+1] = key;
        }
        unsigned r = sR3;
        if (r > n2) r = n2;
        if (r < 1) r = 1;
        scut = (n2 > 0) ? tlist[r-1] : 0u;
    }
    __syncthreads();
    unsigned cut = scut;
    // count selected within bin, reserve once, write
    for (unsigned i = t; i < cnt; i += 256) {
        unsigned u = cval[i];
        if (u > T || (u == T && cidx[i] <= cut)) atomicAdd(&sns, 1u);
    }
    __syncthreads();
    if (t == 0) { sbase = atomicAdd(&dcount[row], sns); sns = 0u; }
    __syncthreads();
    unsigned base = sbase;
    for (unsigned i = t; i < cnt; i += 256) {
        unsigned u = cval[i];
        if (u > T || (u == T && cidx[i] <= cut)) {
            unsigned p = base + atomicAdd(&sns, 1u);
            if (p < ROW_CAP)
                dlist[(size_t)row * ROW_CAP + p] = ((unsigned long long)u << 32) | cidx[i];
        }
    }
}

// ---------------------------------------------------------------------------
// Kernel 6: NN distance. 1024 blocks = (row, 64-sample chunk).
// 256 thr = 64 sample-lanes x 4 mesh-quarters (strided). Fixed-point i64 acc.
// ---------------------------------------------------------------------------
__global__ void __launch_bounds__(256) dist_kernel(
    const float4* __restrict__ meshQ, const float* __restrict__ means,
    const unsigned long long* __restrict__ dlist, const unsigned* __restrict__ dcount,
    unsigned long long* __restrict__ part, unsigned* __restrict__ pcnt)
{
    __shared__ float4 mq[NMESH];
    __shared__ float red[256];
    __shared__ long long redl[256];
    __shared__ unsigned redc[256];
    int blk = blockIdx.x;
    int row = blk >> 4, c = blk & 15;
    int t = threadIdx.x;
    int s = t & 63, q = t >> 6;
    for (int i = t; i < NMESH; i += 256) mq[i] = meshQ[row * NMESH + i];
    unsigned n = dcount[row]; if (n > ROW_CAP) n = ROW_CAP;
    unsigned nbat = (n + 1023u) >> 10;          // uniform across block
    long long accl = 0; unsigned accc = 0;
    __syncthreads();
    for (unsigned b = 0; b < nbat; b++) {
        unsigned g = b * 1024u + (unsigned)(c * 64 + s);
        bool act = false;
        float sx = 0.f, sy = 0.f, sz = 0.f;
        if (g < n) {
            unsigned long long e = dlist[(size_t)row * ROW_CAP + g];
            unsigned uval = (unsigned)(e >> 32);
            unsigned idx  = (unsigned)e;
            if (uval > HALF_BITS) {
                act = true;
                const float* gm = means + ((size_t)row * HW_N + idx) * 3;
                sx = gm[0]; sy = gm[1]; sz = gm[2];
            }
        }
        float m0 = 3.4e38f, m1 = 3.4e38f, m2 = 3.4e38f, m3 = 3.4e38f;
        if (act) {
            int p = q;
            for (int j = 0; j < 97; j++) {
                float4 a0 = mq[p], a1 = mq[p+4], a2 = mq[p+8], a3 = mq[p+12];
                float d0 = fmaf(sx, a0.x, fmaf(sy, a0.y, sz * a0.z));
                float d1 = fmaf(sx, a1.x, fmaf(sy, a1.y, sz * a1.z));
                float d2 = fmaf(sx, a2.x, fmaf(sy, a2.y, sz * a2.z));
                float d3 = fmaf(sx, a3.x, fmaf(sy, a3.y, sz * a3.z));
                m0 = fminf(m0, fmaf(-2.0f, d0, a0.w));
                m1 = fminf(m1, fmaf(-2.0f, d1, a1.w));
                m2 = fminf(m2, fmaf(-2.0f, d2, a2.w));
                m3 = fminf(m3, fmaf(-2.0f, d3, a3.w));
                p += 16;
            }
            {   // tail point j=388: p = q + 1552
                float4 a = mq[q + 1552];
                float dd = fmaf(sx, a.x, fmaf(sy, a.y, sz * a.z));
                m0 = fminf(m0, fmaf(-2.0f, dd, a.w));
            }
        }
        red[t] = fminf(fminf(m0, m1), fminf(m2, m3));
        __syncthreads();
        if (q == 0 && act) {
            float mn = fminf(fminf(red[s], red[s+64]), fminf(red[s+128], red[s+192]));
            float sa = fmaf(sx, sx, fmaf(sy, sy, sz * sz));
            float d2 = fmaxf(mn + sa, 0.0f);
            accl += (long long)((double)d2 * FIX_SCALE);
            accc += 1u;
        }
        __syncthreads();
    }
    redl[t] = accl; redc[t] = accc;
    __syncthreads();
    for (int off = 128; off > 0; off >>= 1) {
        if (t < off) { redl[t] += redl[t+off]; redc[t] += redc[t+off]; }
        __syncthreads();
    }
    if (t == 0) { part[blk] = (unsigned long long)redl[0]; pcnt[blk] = redc[0]; }
}

// ---------------------------------------------------------------------------
// Kernel 7: final integer reduce (order-invariant -> bit-deterministic).
// ---------------------------------------------------------------------------
__global__ void __launch_bounds__(256) finish_kernel(
    const unsigned long long* __restrict__ part, const unsigned* __restrict__ pcnt,
    float* __restrict__ out)
{
    __shared__ long long rs[256];
    __shared__ unsigned rc[256];
    int t = threadIdx.x;
    long long s = 0; unsigned c = 0;
#pragma unroll
    for (int k = 0; k < 4; k++) { s += (long long)part[t + k*256]; c += pcnt[t + k*256]; }
    rs[t] = s; rc[t] = c;
    __syncthreads();
    for (int off = 128; off > 0; off >>= 1) {
        if (t < off) { rs[t] += rs[t+off]; rc[t] += rc[t+off]; }
        __syncthreads();
    }
    if (t == 0) {
        double sum = (double)rs[0] / FIX_SCALE;
        unsigned n = rc[0] ? rc[0] : 1u;
        out[0] = (float)(sum / (double)n);
    }
}

extern "C" void kernel_launch(void* const* d_in, const int* in_sizes, int n_in,
                              void* d_out, int out_size, void* d_ws, size_t ws_size,
                              hipStream_t stream) {
    const float* hp    = (const float*)d_in[0];
    const float* means = (const float*)d_in[1];
    const float* mask  = (const float*)d_in[2];
    const int*   hv    = (const int*)  d_in[3];
    const float* vtl   = (const float*)d_in[4];
    const float* vtr   = (const float*)d_in[5];
    const float* sdl   = (const float*)d_in[6];
    const float* sdr   = (const float*)d_in[7];
    const float* pdl   = (const float*)d_in[8];
    const float* pdr   = (const float*)d_in[9];
    float* out = (float*)d_out;

    char* ws = (char*)d_ws;
    unsigned*           ghist   = (unsigned*)(ws + OFF_GHIST);
    unsigned long long* cand    = (unsigned long long*)(ws + OFF_CAND);
    unsigned*           ccount  = (unsigned*)(ws + OFF_CCOUNT);
    unsigned*           dcount  = (unsigned*)(ws + OFF_DCOUNT);
    unsigned*           params  = (unsigned*)(ws + OFF_PARAMS);
    unsigned long long* dlist   = (unsigned long long*)(ws + OFF_DLIST);
    float4*             meshQ   = (float4*)(ws + OFF_MESH);
    unsigned long long* part    = (unsigned long long*)(ws + OFF_PART);
    unsigned*           pcnt    = (unsigned*)(ws + OFF_PCNT);

    mesh_zero_kernel<<<128 + ZB, 256, 0, stream>>>(hp, hv, vtl, vtr, sdl, sdr, pdl, pdr,
                                                   meshQ, (uint4*)ghist);
    hist_kernel<<<NROW * 16, 256, 0, stream>>>(mask, hv, ghist);
    select_bin_kernel<<<NROW, 256, 0, stream>>>(ghist, hv, params);
    collect_kernel<<<NROW * 16, 256, 0, stream>>>(mask, params, cand, ccount, dlist, dcount);
    finalize_kernel<<<NROW, 256, 0, stream>>>(cand, ccount, params, dlist, dcount);
    dist_kernel<<<NROW * 16, 256, 0, stream>>>(meshQ, means, dlist, dcount, part, pcnt);
    finish_kernel<<<1, 256, 0, stream>>>(part, pcnt, out);
}